// Round 9
// baseline (978.215 us; speedup 1.0000x reference)
//
#include <hip/hip_runtime.h>

// GraphTripleConvNet, fully linear -> aggressive weight composition.
// Round 10: revert to R5-passing structure (R9's K-split core-dumped twice on
// different nodes -> abandoned). Same lever, smaller hammer: GEMM_A's serial
// K-iteration count (the fusedAB critical path) cut 24 -> 12 via BK 64->128
// on the A-side only (template param on the R5-verified core; XOR swizzle
// mask generalizes 7->15). A-branch LDS 24->48KB (3 blocks/CU; measured
// occupancy was ~2.6 anyway). B/C/preamble/fallback stay BK=64.
//
// Per layer (fused path):
//   fusedPC : pool_t (6-seg tSO)  ||  objSO = obj @ [Wp_s|Wp_o]
//   fusedAB : GEMM_A (BK=128) new_obj=(tSO@WW + ns*c1p + no*c2p)/deg + b34c ||
//             GEMM_B new_pred[e]=pred@Wp_p + b12p + objSO[s_e][:256] + objSO[o_e][256:]

#define NTRI 60000
#define NOBJ 20000
#define DD 256
#define HH 512

typedef __attribute__((ext_vector_type(8))) short bf16x8;
typedef __attribute__((ext_vector_type(4))) float f32x4;

#define GLDS(gp, lp) __builtin_amdgcn_global_load_lds( \
    (const __attribute__((address_space(1))) void*)(gp), \
    (__attribute__((address_space(3))) void*)(lp), 16, 0, 0)

__device__ __forceinline__ unsigned short f2bf(float f){
  unsigned int x = __builtin_bit_cast(unsigned int, f);
  x += 0x7fffu + ((x >> 16) & 1u);   // RNE
  return (unsigned short)(x >> 16);
}
__device__ __forceinline__ float bf2f(unsigned short u){
  return __builtin_bit_cast(float, (unsigned int)u << 16);
}

// bijective XCD-chunked swizzle (m204): consecutive logical ids (panel-sharing
// n-tiles) land on the SAME XCD chunk -> operand reread = L2 hit.
__device__ __forceinline__ int xcd_chunk(int b, int n){
  const int q = n >> 3, r = n & 7;
  const int x = b & 7, i = b >> 3;
  return (x < r ? x * (q + 1) : r * (q + 1) + (x - r) * q) + i;
}

// ---------------------------------------------------------------------------
// GEMM core: C(MxN) = A(MxK,bf16) @ Bt(NxK,bf16)^T [+ epilogue]. BMxBN tile,
// BK in {64,128}, 4 waves (2x2), each wave (BM/32)x(BN/32) frags of
// 16x16x32 mfma. K%BK==0, N%BN==0; M guarded. Single-buffer 2-sync loop.
// LDS XOR-swizzled (chunk mask BK/8-1): GLDS dest linear, global source kp
// carries the inverse permutation; read applies the same XOR (both-sides rule).
// MODE 0: bf16 + bias[col].
// MODE 2: bf16, v = (acc + ns*bias + no*bias2)/max(ns+no,1) + bias3.
// MODE 6: fp32, same epilogue as MODE 2.
// MODE 3: bf16 transposed store out[col*ldT+row].
// MODE 5: bf16, no bias.
// MODE 7: bf16, v = acc + bias[col] + gath[s_e][col] + gath[o_e][256+col].
// MODE 8: fp32, same epilogue as MODE 7.
// ---------------------------------------------------------------------------
template<int MODE, int BM, int BN, int BK>
__device__ __forceinline__ void gemm_core(
    unsigned short* sA, unsigned short* sB,
    const unsigned short* __restrict__ A,
    const unsigned short* __restrict__ Bt,
    const float* __restrict__ bias,
    const float* __restrict__ bias2,
    const float* __restrict__ bias3,
    const int* __restrict__ cntS,
    const int* __restrict__ cntO,
    const int2* __restrict__ eidx,
    const unsigned short* __restrict__ gath,
    void* __restrict__ out0,
    int m0, int n0, int M, int K, int N, int ldT)
{
  constexpr int MI = BM / 32;            // A frags per wave (m-dir)
  constexpr int NI = BN / 32;
  constexpr int CPR   = BK / 8;          // 16B chunks per LDS row
  constexpr int CMASK = CPR - 1;         // XOR swizzle mask (7 or 15)
  constexpr int RPP   = 2048 / BK;       // rows staged per GLDS pass
  constexpr int APASS = BM / RPP;
  constexpr int BPASS = BN / RPP;
  const int tid  = threadIdx.x;
  const int lane = tid & 63;
  const int wv   = tid >> 6;
  const int wm   = wv & 1;
  const int wn   = wv >> 1;
  const int quad = lane >> 4;
  const int l15  = lane & 15;

  f32x4 acc[MI][NI] = {};

  const int rr = tid / CPR;                              // staging row in pass
  const int kp = ((tid & CMASK) ^ (rr & CMASK)) << 3;    // pre-swizzled k chunk
  const unsigned short* gA[APASS];
  const unsigned short* gB[BPASS];
#pragma unroll
  for (int i = 0; i < APASS; ++i){
    int r = m0 + rr + RPP * i;           // (r & CMASK) == (rr & CMASK): kp valid
    r = (r < M) ? r : (M - 1);           // clamped (dup data, consistent swz); stores guarded
    gA[i] = A + (size_t)r * K + kp;
  }
#pragma unroll
  for (int i = 0; i < BPASS; ++i)
    gB[i] = Bt + (size_t)(n0 + rr + RPP * i) * K + kp;

  const int swq = l15 & CMASK;           // == frag_row & CMASK (offsets are mult of 16)
  const int t8  = tid * 8;

  for (int k0 = 0; k0 < K; k0 += BK){
    __syncthreads();
#pragma unroll
    for (int i = 0; i < APASS; ++i){ GLDS(gA[i], sA + t8 + 2048 * i); gA[i] += BK; }
#pragma unroll
    for (int i = 0; i < BPASS; ++i){ GLDS(gB[i], sB + t8 + 2048 * i); gB[i] += BK; }
    __syncthreads();
#pragma unroll
    for (int kc = 0; kc < BK / 32; ++kc){
      bf16x8 af[MI], bq[NI];
      const int sw = (((kc * 4 + quad) ^ swq) << 3);     // swizzled read offset
#pragma unroll
      for (int mt = 0; mt < MI; ++mt)
        af[mt] = *(const bf16x8*)(sA + (wm*(BM/2) + mt*16 + l15)*BK + sw);
#pragma unroll
      for (int nt = 0; nt < NI; ++nt)
        bq[nt] = *(const bf16x8*)(sB + (wn*(BN/2) + nt*16 + l15)*BK + sw);
#pragma unroll
      for (int mt = 0; mt < MI; ++mt)
#pragma unroll
        for (int nt = 0; nt < NI; ++nt)
          acc[mt][nt] = __builtin_amdgcn_mfma_f32_16x16x32_bf16(af[mt], bq[nt], acc[mt][nt], 0, 0, 0);
    }
  }

  // C/D layout: col = l15, row = quad*4 + reg   [m89-verified]
  if constexpr (MODE == 3){
    unsigned short* outp = (unsigned short*)out0;
#pragma unroll
    for (int mt = 0; mt < MI; ++mt){
      const int rb = m0 + wm*(BM/2) + mt*16 + quad*4;
#pragma unroll
      for (int nt = 0; nt < NI; ++nt){
        const int col = n0 + wn*(BN/2) + nt*16 + l15;
        ushort4 r4;
        r4.x = f2bf(acc[mt][nt][0]); r4.y = f2bf(acc[mt][nt][1]);
        r4.z = f2bf(acc[mt][nt][2]); r4.w = f2bf(acc[mt][nt][3]);
        *(ushort4*)(outp + (size_t)col * ldT + rb) = r4;
      }
    }
  } else if constexpr (MODE == 7 || MODE == 8){
#pragma unroll
    for (int mt = 0; mt < MI; ++mt){
      const int rb = m0 + wm*(BM/2) + mt*16 + quad*4;
#pragma unroll
      for (int r = 0; r < 4; ++r){
        const int row = rb + r;
        if (row >= M) continue;
        const int2 ei = eidx[row];
        const unsigned short* srow = gath + (size_t)ei.x * 512;
        const unsigned short* orow = gath + (size_t)ei.y * 512 + 256;
#pragma unroll
        for (int nt = 0; nt < NI; ++nt){
          const int col = n0 + wn*(BN/2) + nt*16 + l15;
          const float v = acc[mt][nt][r] + bias[col] + bf2f(srow[col]) + bf2f(orow[col]);
          if constexpr (MODE == 8) ((float*)out0)[(size_t)row * N + col] = v;
          else ((unsigned short*)out0)[(size_t)row * N + col] = f2bf(v);
        }
      }
    }
  } else {
#pragma unroll
    for (int mt = 0; mt < MI; ++mt){
      const int rb = m0 + wm*(BM/2) + mt*16 + quad*4;
#pragma unroll
      for (int nt = 0; nt < NI; ++nt){
        const int col = n0 + wn*(BN/2) + nt*16 + l15;
#pragma unroll
        for (int r = 0; r < 4; ++r){
          const int row = rb + r;
          if (row >= M) continue;
          float v = acc[mt][nt][r];
          if constexpr (MODE == 0) v += bias[col];
          if constexpr (MODE == 2 || MODE == 6){
            const float ns = (float)cntS[row], no = (float)cntO[row];
            v = (v + ns * bias[col] + no * bias2[col]) / fmaxf(ns + no, 1.f) + bias3[col];
          }
          if constexpr (MODE == 6) ((float*)out0)[(size_t)row * N + col] = v;
          else                     ((unsigned short*)out0)[(size_t)row * N + col] = f2bf(v);
        }
      }
    }
  }
}

// standalone wrapper (preamble weight GEMMs + fallback path), grid.z batching.
template<int MODE, int BM, int BN>
__global__ __launch_bounds__(256) void gemm64_k(
    const unsigned short* __restrict__ A,
    const unsigned short* __restrict__ Bt,
    const float* __restrict__ bias,
    const float* __restrict__ bias2,
    const float* __restrict__ bias3,
    const int* __restrict__ cntS,
    const int* __restrict__ cntO,
    const int2* __restrict__ eidx,
    const unsigned short* __restrict__ gath,
    void* __restrict__ out0,
    int M, int K, int N, int ldT,
    long strideA, long strideB, long strideC)
{
  __shared__ __align__(16) unsigned short smem[BM*64 + BN*64];
  const int nxy = gridDim.x * gridDim.y;
  int bid = xcd_chunk(blockIdx.y * gridDim.x + blockIdx.x, nxy);
  const int m0 = (bid / gridDim.x) * BM;
  const int n0 = (bid % gridDim.x) * BN;
  const size_t zb = blockIdx.z;
  const unsigned short* Az  = A + zb * strideA;
  const unsigned short* Btz = Bt + zb * strideB;
  void* outz;
  if constexpr (MODE == 3) outz = (unsigned short*)out0 + zb * strideC;
  else if constexpr (MODE == 6 || MODE == 8) outz = (char*)out0 + zb * strideC * 4;
  else outz = (char*)out0 + zb * strideC * 2;
  gemm_core<MODE,BM,BN,64>(smem, smem + BM*64, Az, Btz, bias, bias2, bias3,
                           cntS, cntO, eidx, gath, outz, m0, n0, M, K, N, ldT);
}

// --- edges dtype autodetect ---
__global__ __launch_bounds__(256) void detect_k(const int* __restrict__ e, int* __restrict__ flag)
{
  const int i = blockIdx.x * 256 + threadIdx.x;
  if (i >= NTRI) return;
  if (e[2*i + 1] != 0) atomicOr(flag, 1);   // any nonzero odd word => int32 layout
}

__global__ __launch_bounds__(256) void norm_k(const int* __restrict__ e, const int* __restrict__ flag,
                                              int2* __restrict__ eidx)
{
  const int i = blockIdx.x * 256 + threadIdx.x;
  if (i >= NTRI) return;
  int s, o;
  if (*flag){ s = e[2*i]; o = e[2*i + 1]; }
  else      { s = e[4*i]; o = e[4*i + 2]; }
  s = min(max(s, 0), NOBJ - 1);
  o = min(max(o, 0), NOBJ - 1);
  eidx[i] = make_int2(s, o);
}

__global__ __launch_bounds__(256) void deg_k(const int2* __restrict__ eidx,
                                             int* __restrict__ cnt_s, int* __restrict__ cnt_o)
{
  const int i = blockIdx.x * 256 + threadIdx.x;
  if (i >= NTRI) return;
  atomicAdd(&cnt_s[eidx[i].x], 1);
  atomicAdd(&cnt_o[eidx[i].y], 1);
}

__global__ __launch_bounds__(1024) void scan_k(const int* __restrict__ cnt_s,
                                               const int* __restrict__ cnt_o,
                                               int* __restrict__ offs)
{
  __shared__ int sd[1024];
  __shared__ int carry;
  if (threadIdx.x == 0) carry = 0;
  __syncthreads();
  const int nIter = (NOBJ + 1023) / 1024;
  for (int it = 0; it < nIter; ++it){
    const int i = it * 1024 + (int)threadIdx.x;
    const int v = (i < NOBJ) ? (cnt_s[i] + cnt_o[i]) : 0;
    sd[threadIdx.x] = v;
    __syncthreads();
    for (int off = 1; off < 1024; off <<= 1){
      const int t = ((int)threadIdx.x >= off) ? sd[threadIdx.x - off] : 0;
      __syncthreads();
      sd[threadIdx.x] += t;
      __syncthreads();
    }
    if (i < NOBJ) offs[i] = carry + sd[threadIdx.x] - v;
    __syncthreads();
    if (threadIdx.x == 0){
      carry += sd[1023];
      if (it == nIter - 1) offs[NOBJ] = carry;
    }
    __syncthreads();
  }
}

// slot payload: (2*e+role, other_object_index)
__global__ __launch_bounds__(256) void fill_k(const int2* __restrict__ eidx,
                                              int* __restrict__ cursor, int2* __restrict__ slots)
{
  const int i = blockIdx.x * 256 + threadIdx.x;
  if (i >= NTRI) return;
  const int2 e = eidx[i];
  slots[atomicAdd(&cursor[e.x], 1)] = make_int2(2*i,     e.y);   // subject role
  slots[atomicAdd(&cursor[e.y], 1)] = make_int2(2*i + 1, e.x);   // object role
}

// tSO[o][1536] = [ns*obj[o] | SUMs pred | SUMs obj[oidx] | SUMo obj[sidx] | SUMo pred | no*obj[o]]
// ushort4 loads (8B/lane), 4 slot-groups in parallel, LDS tree-combine.
__device__ __forceinline__ void pool_core(
    const unsigned short* __restrict__ obj, const unsigned short* __restrict__ pred,
    const int* __restrict__ offs, const int2* __restrict__ slots,
    const int* __restrict__ cnt_s, const int* __restrict__ cnt_o,
    unsigned short* __restrict__ tSO, int o, float (*red)[4][256])
{
  const int tid  = (int)threadIdx.x;
  const int g    = tid >> 6;
  const int lane = tid & 63;
  const int c4   = lane << 2;
  const int b0 = offs[o], b1 = offs[o + 1];
  float sp0=0.f, sp1=0.f, sp2=0.f, sp3=0.f;
  float so0=0.f, so1=0.f, so2=0.f, so3=0.f;
  float oo0=0.f, oo1=0.f, oo2=0.f, oo3=0.f;
  float op0=0.f, op1=0.f, op2=0.f, op3=0.f;
  for (int j = b0 + g; j < b1; j += 4){
    const int2 sl = slots[j];
    const ushort4 pv = *(const ushort4*)(pred + (size_t)(sl.x >> 1) * DD + c4);
    const ushort4 ov = *(const ushort4*)(obj  + (size_t)sl.y * DD + c4);
    const float p0 = bf2f(pv.x), p1 = bf2f(pv.y), p2 = bf2f(pv.z), p3 = bf2f(pv.w);
    const float q0 = bf2f(ov.x), q1 = bf2f(ov.y), q2 = bf2f(ov.z), q3 = bf2f(ov.w);
    if (sl.x & 1){ op0+=p0; op1+=p1; op2+=p2; op3+=p3; oo0+=q0; oo1+=q1; oo2+=q2; oo3+=q3; }
    else         { sp0+=p0; sp1+=p1; sp2+=p2; sp3+=p3; so0+=q0; so1+=q1; so2+=q2; so3+=q3; }
  }
  red[g][0][c4+0]=sp0; red[g][0][c4+1]=sp1; red[g][0][c4+2]=sp2; red[g][0][c4+3]=sp3;
  red[g][1][c4+0]=so0; red[g][1][c4+1]=so1; red[g][1][c4+2]=so2; red[g][1][c4+3]=so3;
  red[g][2][c4+0]=oo0; red[g][2][c4+1]=oo1; red[g][2][c4+2]=oo2; red[g][2][c4+3]=oo3;
  red[g][3][c4+0]=op0; red[g][3][c4+1]=op1; red[g][3][c4+2]=op2; red[g][3][c4+3]=op3;
  __syncthreads();
  unsigned short* dst = tSO + (size_t)o * 1536;
#define TOTW(s, off) { \
    const float4 t0 = *(const float4*)&red[0][s][c4]; \
    const float4 t1 = *(const float4*)&red[1][s][c4]; \
    const float4 t2 = *(const float4*)&red[2][s][c4]; \
    const float4 t3 = *(const float4*)&red[3][s][c4]; \
    ushort4 w; \
    w.x = f2bf(t0.x + t1.x + t2.x + t3.x); \
    w.y = f2bf(t0.y + t1.y + t2.y + t3.y); \
    w.z = f2bf(t0.z + t1.z + t2.z + t3.z); \
    w.w = f2bf(t0.w + t1.w + t2.w + t3.w); \
    *(ushort4*)(dst + (off) + c4) = w; }
  if (g == 0){
    const ushort4 ob = *(const ushort4*)(obj + (size_t)o * DD + c4);
    const float ns = (float)cnt_s[o];
    ushort4 w;
    w.x = f2bf(ns * bf2f(ob.x)); w.y = f2bf(ns * bf2f(ob.y));
    w.z = f2bf(ns * bf2f(ob.z)); w.w = f2bf(ns * bf2f(ob.w));
    *(ushort4*)(dst + c4) = w;
    TOTW(0, 256);
  } else if (g == 1){
    TOTW(1, 512);
  } else if (g == 2){
    TOTW(2, 768);
    const ushort4 ob = *(const ushort4*)(obj + (size_t)o * DD + c4);
    const float no = (float)cnt_o[o];
    ushort4 w;
    w.x = f2bf(no * bf2f(ob.x)); w.y = f2bf(no * bf2f(ob.y));
    w.z = f2bf(no * bf2f(ob.z)); w.w = f2bf(no * bf2f(ob.w));
    *(ushort4*)(dst + 1280 + c4) = w;
  } else {
    TOTW(3, 1024);
  }
#undef TOTW
}

__global__ __launch_bounds__(256) void pool_t_k(
    const unsigned short* __restrict__ obj, const unsigned short* __restrict__ pred,
    const int* __restrict__ offs, const int2* __restrict__ slots,
    const int* __restrict__ cnt_s, const int* __restrict__ cnt_o,
    unsigned short* __restrict__ tSO)
{
  __shared__ __align__(16) float red[4][4][256];
  pool_core(obj, pred, offs, slots, cnt_s, cnt_o, tSO, blockIdx.x, red);
}

// L1 fused: pool_t (blocks [0,NOBJ)) || GEMM_C objSO = obj @ WpSO (128x64, BK=64)
__global__ __launch_bounds__(256) void fusedPC_k(
    const unsigned short* __restrict__ obj, const unsigned short* __restrict__ pred,
    const int* __restrict__ offs, const int2* __restrict__ slots,
    const int* __restrict__ cnt_s, const int* __restrict__ cnt_o,
    unsigned short* __restrict__ tSO,
    const unsigned short* __restrict__ WpSOT, unsigned short* __restrict__ objSO)
{
  __shared__ __align__(16) char smem[24576];   // max(pool 16KB, gemm 24KB)
  int b = blockIdx.x;
  if (b < NOBJ){
    pool_core(obj, pred, offs, slots, cnt_s, cnt_o, tSO, b, (float (*)[4][256])smem);
  } else {
    constexpr int GXC = HH / 64;                       // 8
    const int NC = GXC * ((NOBJ + 127) / 128);         // 1256
    b = xcd_chunk(b - NOBJ, NC);
    const int m0 = (b / GXC) * 128, n0 = (b % GXC) * 64;
    gemm_core<5,128,64,64>((unsigned short*)smem, (unsigned short*)smem + 128*64,
        obj, WpSOT, nullptr, nullptr, nullptr, nullptr, nullptr, nullptr, nullptr,
        objSO, m0, n0, NOBJ, 256, HH, 0);
  }
}

// L2 fused: GEMM_A (BK=128, blocks [0,NA)) || GEMM_B (BK=64, fused gather).
// smem sized for the A-branch (128x128 + 64x128 = 48KB); B-branch uses a prefix.
template<int MA, int MB>
__global__ __launch_bounds__(256) void fusedAB_k(
    const unsigned short* __restrict__ tSO, const unsigned short* __restrict__ WWTl,
    const float* __restrict__ c1p, const float* __restrict__ c2p,
    const float* __restrict__ b34c,
    const int* __restrict__ cnt_s, const int* __restrict__ cnt_o,
    void* __restrict__ outA,
    const unsigned short* __restrict__ predc, const unsigned short* __restrict__ WpPTl,
    const float* __restrict__ biasB, const int2* __restrict__ eidx,
    const unsigned short* __restrict__ objSO, void* __restrict__ outB)
{
  __shared__ __align__(16) unsigned short smem[128*128 + 64*128];   // 48KB
  constexpr int GX = DD / 64;                          // 4
  const int NA = GX * ((NOBJ + 127) / 128);            // 628
  int b = blockIdx.x;
  if (b < NA){
    b = xcd_chunk(b, NA);
    const int m0 = (b / GX) * 128, n0 = (b % GX) * 64;
    gemm_core<MA,128,64,128>(smem, smem + 128*128, tSO, WWTl, c1p, c2p, b34c,
        cnt_s, cnt_o, nullptr, nullptr, outA, m0, n0, NOBJ, 1536, DD, 0);
  } else {
    const int NB = GX * ((NTRI + 127) / 128);          // 1876
    b = xcd_chunk(b - NA, NB);
    const int m0 = (b / GX) * 128, n0 = (b % GX) * 64;
    gemm_core<MB,128,64,64>(smem, smem + 128*64, predc, WpPTl, biasB, nullptr, nullptr,
        nullptr, nullptr, eidx, objSO, outB, m0, n0, NTRI, 256, DD, 0);
  }
}

// fallback path only: new_pred[e][c] = predP[e][c] + objSO[s_e][c] + objSO[o_e][256+c]
template<int OUT>
__global__ __launch_bounds__(256) void add_k(
    const unsigned short* __restrict__ predP, const unsigned short* __restrict__ objSO,
    const int2* __restrict__ eidx, void* __restrict__ outp)
{
  const int i = blockIdx.x * 256 + threadIdx.x;
  if (i >= NTRI * 64) return;
  const int e  = i >> 6;
  const int c4 = (i & 63) << 2;
  const int2 ei = eidx[e];
  const ushort4 a = *(const ushort4*)(predP + (size_t)e * DD + c4);
  const ushort4 s = *(const ushort4*)(objSO + (size_t)ei.x * 512 + c4);
  const ushort4 o = *(const ushort4*)(objSO + (size_t)ei.y * 512 + 256 + c4);
  float v0 = bf2f(a.x) + bf2f(s.x) + bf2f(o.x);
  float v1 = bf2f(a.y) + bf2f(s.y) + bf2f(o.y);
  float v2 = bf2f(a.z) + bf2f(s.z) + bf2f(o.z);
  float v3 = bf2f(a.w) + bf2f(s.w) + bf2f(o.w);
  if constexpr (OUT){
    float4 r = make_float4(v0, v1, v2, v3);
    *(float4*)((float*)outp + (size_t)e * DD + c4) = r;
  } else {
    ushort4 r;
    r.x = f2bf(v0); r.y = f2bf(v1); r.z = f2bf(v2); r.w = f2bf(v3);
    *(ushort4*)((unsigned short*)outp + (size_t)e * DD + c4) = r;
  }
}

// fp32 -> bf16 flat (vector x4)
__global__ __launch_bounds__(256) void conv_f2b_k(const float* __restrict__ x,
                                                  unsigned short* __restrict__ y, int n4)
{
  const int i = blockIdx.x * 256 + threadIdx.x;
  if (i >= n4) return;
  const float4 v = ((const float4*)x)[i];
  ushort4 r;
  r.x = f2bf(v.x); r.y = f2bf(v.y); r.z = f2bf(v.z); r.w = f2bf(v.w);
  ((ushort4*)y)[i] = r;
}

// batched (L=5) transpose-convert: Wt[l][n][k] = bf16(W[l][k][colOff+n]), K=512
__global__ __launch_bounds__(256) void conv_wT_k(
    const float* __restrict__ W, unsigned short* __restrict__ Wt,
    int N, int ldW, int colOff, long wLS, long oLS)
{
  const int idx = blockIdx.x * 256 + threadIdx.x;
  const int per = N * 512;
  if (idx >= 5 * per) return;
  const int l = idx / per;
  const int r = idx - l * per;
  const int n = r >> 9;
  const int k = r & 511;
  Wt[l * oLS + (size_t)n * 512 + k] = f2bf(W[l * wLS + (size_t)k * ldW + colOff + n]);
}

// cb2[l][0..1280) = b1[l]@W2[l] + b2[l];  b34c[l][0..256) = b3[l]@W4[l] + b4[l]
__global__ __launch_bounds__(256) void biascomp_k(
    const float* __restrict__ b1, const float* __restrict__ W2, const float* __restrict__ b2,
    const float* __restrict__ b3, const float* __restrict__ W4, const float* __restrict__ b4,
    float* __restrict__ cb2, float* __restrict__ b34c)
{
  const int idx = blockIdx.x * 256 + threadIdx.x;
  if (idx < 5 * 1280){
    const int l = idx / 1280, n = idx - l * 1280;
    float s = b2[l * 1280 + n];
    for (int k = 0; k < 512; ++k)
      s += b1[l * 512 + k] * W2[(size_t)l * 512 * 1280 + (size_t)k * 1280 + n];
    cb2[idx] = s;
  } else if (idx < 5 * 1280 + 5 * 256){
    const int j = idx - 6400;
    const int l = j / 256, n = j - l * 256;
    float s = b4[l * 256 + n];
    for (int k = 0; k < 512; ++k)
      s += b3[l * 512 + k] * W4[(size_t)l * 512 * 256 + (size_t)k * 256 + n];
    b34c[j] = s;
  }
}

// c1p[l][n] = c1[l]@W34c[l][:,n],  c2p[l][n] = c2[l]@W34c[l][:,n]   (W34T bf16 [l][n][k])
__global__ __launch_bounds__(256) void compose_c_k(
    const float* __restrict__ cb2, const unsigned short* __restrict__ W34T,
    float* __restrict__ c1p, float* __restrict__ c2p)
{
  const int idx = blockIdx.x * 256 + threadIdx.x;
  if (idx >= 5 * 256) return;
  const int l = idx >> 8, n = idx & 255;
  const unsigned short* wr = W34T + ((size_t)l * 256 + n) * 512;
  float a = 0.f, b = 0.f;
  for (int k = 0; k < 512; ++k){
    const float w = bf2f(wr[k]);
    a += cb2[l * 1280 + k] * w;
    b += cb2[l * 1280 + 768 + k] * w;
  }
  c1p[idx] = a;
  c2p[idx] = b;
}

extern "C" void kernel_launch(void* const* d_in, const int* in_sizes, int n_in,
                              void* d_out, int out_size, void* d_ws, size_t ws_size,
                              hipStream_t stream)
{
  const float* obj_in  = (const float*)d_in[0];
  const float* pred_in = (const float*)d_in[1];
  const int*   edges   = (const int*)d_in[2];
  const float* W1 = (const float*)d_in[3];
  const float* b1 = (const float*)d_in[4];
  const float* W2 = (const float*)d_in[5];
  const float* b2 = (const float*)d_in[6];
  const float* W3 = (const float*)d_in[7];
  const float* b3 = (const float*)d_in[8];
  const float* W4 = (const float*)d_in[9];
  const float* b4 = (const float*)d_in[10];
  float* out = (float*)d_out;

  char* p = (char*)d_ws;
  auto alloc = [&](size_t bytes){ char* r = p; p += (bytes + 255) & ~(size_t)255; return r; };

  // weight staging (bf16) — DEAD after preamble; objSO overlays this region
  // (22.3MB contiguous W1bf..Wso_rm >= 20.5MB) during the layer loop.
  unsigned short* W1bf  = (unsigned short*)alloc((size_t)5 * 768 * 512 * 2);
  unsigned short* W2pT  = (unsigned short*)alloc((size_t)5 * 256 * 512 * 2);
  unsigned short* W2sT  = (unsigned short*)alloc((size_t)5 * 512 * 512 * 2);
  unsigned short* W2oT  = (unsigned short*)alloc((size_t)5 * 512 * 512 * 2);
  unsigned short* W3bf  = (unsigned short*)alloc((size_t)5 * 512 * 512 * 2);
  unsigned short* W4T   = (unsigned short*)alloc((size_t)5 * 256 * 512 * 2);
  unsigned short* Wso_rm = (unsigned short*)alloc((size_t)5 * 1536 * 512 * 2); // W1@[W2s;W2o]
  // composed weights (LIVE through layers)
  unsigned short* W34T   = (unsigned short*)alloc((size_t)5 * 256 * 512 * 2);  // (W3@W4)^T (preamble only)
  unsigned short* WWT    = (unsigned short*)alloc((size_t)5 * 256 * 1536 * 2); // (Wso@W34)^T
  unsigned short* WpSOT  = (unsigned short*)alloc((size_t)5 * 512 * 256 * 2);  // [Wp_s|Wp_o]^T
  unsigned short* WpPT   = (unsigned short*)alloc((size_t)5 * 256 * 256 * 2);  // Wp_p^T
  float* cb2  = (float*)alloc((size_t)5 * 1280 * 4);
  float* b34c = (float*)alloc((size_t)5 * 256 * 4);
  float* c1p  = (float*)alloc((size_t)5 * 256 * 4);
  float* c2p  = (float*)alloc((size_t)5 * 256 * 4);
  // activations
  unsigned short* objA    = (unsigned short*)alloc((size_t)NOBJ * DD * 2);   // 10.2 MB
  unsigned short* objB    = (unsigned short*)alloc((size_t)NOBJ * DD * 2);   // 10.2 MB
  unsigned short* pred_bf = (unsigned short*)alloc((size_t)NTRI * DD * 2);   // 30.7 MB
  unsigned short* tSO     = (unsigned short*)alloc((size_t)NOBJ * 1536 * 2); // 61.4 MB
  // fused path: objSO overlays dead preamble staging (NOT tSO)
  unsigned short* objSO_pre = W1bf;                               // 20.5 MB
  // fallback overlays into tSO (serial path only):
  unsigned short* objSO_fb = tSO;
  unsigned short* predP    = tSO + (size_t)NOBJ * 512;
  // CSR
  int2* eidx  = (int2*)alloc((size_t)NTRI * 8);
  int*  offs  = (int*)alloc((NOBJ + 1) * 4);
  int2* slots = (int2*)alloc((size_t)2 * NTRI * 8);
  int* cnt_s  = (int*)alloc(NOBJ * 4);
  int* cnt_o  = (int*)alloc(NOBJ * 4);
  int* cursor = (int*)alloc(NOBJ * 4);
  int* flag   = (int*)alloc(256);

  // pred double-buffer for the fused-epilogue path, only if workspace allows.
  unsigned short* predB = nullptr;
  {
    const size_t used = (size_t)(p - (char*)d_ws);
    if (ws_size >= used + (size_t)NTRI * DD * 2 + 512)
      predB = (unsigned short*)alloc((size_t)NTRI * DD * 2);
  }

  // ---- CSR preamble (edges are layer-invariant) ----
  (void)hipMemsetAsync(cnt_s, 0, NOBJ * 4, stream);
  (void)hipMemsetAsync(cnt_o, 0, NOBJ * 4, stream);
  (void)hipMemsetAsync(flag, 0, 4, stream);
  const int EB = (NTRI + 255) / 256;
  detect_k<<<EB, 256, 0, stream>>>(edges, flag);
  norm_k<<<EB, 256, 0, stream>>>(edges, flag, eidx);
  deg_k<<<EB, 256, 0, stream>>>(eidx, cnt_s, cnt_o);
  scan_k<<<1, 1024, 0, stream>>>(cnt_s, cnt_o, offs);
  (void)hipMemcpyAsync(cursor, offs, NOBJ * 4, hipMemcpyDeviceToDevice, stream);
  fill_k<<<EB, 256, 0, stream>>>(eidx, cursor, slots);

  // ---- inputs -> bf16 ----
  conv_f2b_k<<<(NOBJ * DD / 4 + 255) / 256, 256, 0, stream>>>(obj_in, objA, NOBJ * DD / 4);
  conv_f2b_k<<<(NTRI * DD / 4 + 255) / 256, 256, 0, stream>>>(pred_in, pred_bf, NTRI * DD / 4);

  // ---- weight staging ----
  conv_f2b_k<<<(5 * 768 * 512 / 4 + 255) / 256, 256, 0, stream>>>(W1, W1bf, 5 * 768 * 512 / 4);
  conv_f2b_k<<<(5 * 512 * 512 / 4 + 255) / 256, 256, 0, stream>>>(W3, W3bf, 5 * 512 * 512 / 4);
  conv_wT_k<<<(5 * 256 * 512 + 255) / 256, 256, 0, stream>>>(W2, W2pT, 256, 1280, 512, 512L*1280, 256L*512);
  conv_wT_k<<<(5 * 512 * 512 + 255) / 256, 256, 0, stream>>>(W2, W2sT, 512, 1280, 0,   512L*1280, 512L*512);
  conv_wT_k<<<(5 * 512 * 512 + 255) / 256, 256, 0, stream>>>(W2, W2oT, 512, 1280, 768, 512L*1280, 512L*512);
  conv_wT_k<<<(5 * 256 * 512 + 255) / 256, 256, 0, stream>>>(W4, W4T,  256, 256,  0,   512L*256,  256L*512);
  biascomp_k<<<30, 256, 0, stream>>>(b1, W2, b2, b3, W4, b4, cb2, b34c);

#define NP5 nullptr, nullptr, nullptr, nullptr, nullptr, nullptr, nullptr
  // ---- weight composition GEMMs (grid.z = 5 layers), 64x64 tiles ----
  gemm64_k<5,64,64><<<dim3(8, 12, 5), 256, 0, stream>>>(W1bf, W2sT, NP5,
      Wso_rm, 768, 512, 512, 0, 768L*512, 512L*512, 1536L*512);
  gemm64_k<5,64,64><<<dim3(8, 12, 5), 256, 0, stream>>>(W1bf, W2oT, NP5,
      Wso_rm + (size_t)768*512, 768, 512, 512, 0, 768L*512, 512L*512, 1536L*512);
  gemm64_k<3,64,64><<<dim3(4, 8, 5), 256, 0, stream>>>(W3bf, W4T, NP5,
      W34T, 512, 512, 256, 512, 512L*512, 256L*512, 256L*512);
  gemm64_k<3,64,64><<<dim3(4, 24, 5), 256, 0, stream>>>(Wso_rm, W34T, NP5,
      WWT, 1536, 512, 256, 1536, 1536L*512, 256L*512, 256L*1536);
  gemm64_k<3,64,64><<<dim3(4, 4, 5), 256, 0, stream>>>(W1bf, W2pT, NP5,
      WpSOT, 256, 512, 256, 256, 768L*512, 256L*512, 512L*256);
  gemm64_k<3,64,64><<<dim3(4, 4, 5), 256, 0, stream>>>(W1bf + (size_t)512*512, W2pT, NP5,
      WpSOT + (size_t)256*256, 256, 512, 256, 256, 768L*512, 256L*512, 512L*256);
  gemm64_k<3,64,64><<<dim3(4, 4, 5), 256, 0, stream>>>(W1bf + (size_t)256*512, W2pT, NP5,
      WpPT, 256, 512, 256, 256, 768L*512, 256L*512, 256L*256);
  compose_c_k<<<5, 256, 0, stream>>>(cb2, W34T, c1p, c2p);

  // ---- layers ----
  unsigned short* objbuf[2]  = { objA, objB };
  unsigned short* predbuf[2] = { pred_bf, predB };
  int cur = 0, pc = 0;
  const int NPC = NOBJ + 8 * ((NOBJ + 127) / 128);          // 20000 + 1256
  const int NAB = 4 * ((NOBJ + 127) / 128) + 4 * ((NTRI + 127) / 128);  // 628 + 1876
  for (int l = 0; l < 5; ++l){
    const unsigned short* objc  = objbuf[cur];
    const unsigned short* predc = predbuf[pc];
    if (predB){
      // L1: pool_t || GEMM_C  (objSO in dead preamble region; no tSO conflict)
      fusedPC_k<<<NPC, 256, 0, stream>>>(objc, predc, offs, slots, cnt_s, cnt_o,
          tSO, WpSOT + (size_t)l*512*256, objSO_pre);
      // L2: GEMM_A (BK=128) || GEMM_B (fused gather epilogue)
      if (l < 4)
        fusedAB_k<2,7><<<NAB, 256, 0, stream>>>(tSO, WWT + (size_t)l*256*1536,
            c1p + l*256, c2p + l*256, b34c + l*256, cnt_s, cnt_o, objbuf[cur ^ 1],
            predc, WpPT + (size_t)l*256*256, cb2 + (size_t)l*1280 + 512, eidx,
            objSO_pre, predbuf[pc ^ 1]);
      else
        fusedAB_k<6,8><<<NAB, 256, 0, stream>>>(tSO, WWT + (size_t)l*256*1536,
            c1p + l*256, c2p + l*256, b34c + l*256, cnt_s, cnt_o, out,
            predc, WpPT + (size_t)l*256*256, cb2 + (size_t)l*1280 + 512, eidx,
            objSO_pre, out + (size_t)NOBJ * DD);
      pc ^= 1;
    } else {
      // fallback: serial launches, objSO overlays tSO, predP + add_k
      pool_t_k<<<NOBJ, 256, 0, stream>>>(objc, predc, offs, slots, cnt_s, cnt_o, tSO);
      const int GY_OBJ = (NOBJ + 127) / 128;
      const int GY_TRI = (NTRI + 127) / 128;
      if (l < 4)
        gemm64_k<2,128,64><<<dim3(4, GY_OBJ), 256, 0, stream>>>(tSO, WWT + (size_t)l*256*1536,
            c1p + l*256, c2p + l*256, b34c + l*256, cnt_s, cnt_o, nullptr, nullptr,
            objbuf[cur ^ 1], NOBJ, 1536, DD, 0, 0, 0, 0);
      else
        gemm64_k<6,128,64><<<dim3(4, GY_OBJ), 256, 0, stream>>>(tSO, WWT + (size_t)l*256*1536,
            c1p + l*256, c2p + l*256, b34c + l*256, cnt_s, cnt_o, nullptr, nullptr,
            out, NOBJ, 1536, DD, 0, 0, 0, 0);
      gemm64_k<5,128,64><<<dim3(8, GY_OBJ), 256, 0, stream>>>(objc, WpSOT + (size_t)l*512*256,
          NP5, objSO_fb, NOBJ, 256, 512, 0, 0, 0, 0);
      gemm64_k<0,128,64><<<dim3(4, GY_TRI), 256, 0, stream>>>(predc, WpPT + (size_t)l*256*256,
          cb2 + (size_t)l*1280 + 512, nullptr, nullptr, nullptr, nullptr, nullptr, nullptr,
          predP, NTRI, 256, DD, 0, 0, 0, 0);
      if (l < 4)
        add_k<0><<<(NTRI * 64 + 255) / 256, 256, 0, stream>>>(predP, objSO_fb, eidx, pred_bf);
      else
        add_k<1><<<(NTRI * 64 + 255) / 256, 256, 0, stream>>>(predP, objSO_fb, eidx, out + (size_t)NOBJ * DD);
    }
    cur ^= 1;
  }
#undef NP5
}